// Round 1
// baseline (73.770 us; speedup 1.0000x reference)
//
#include <hip/hip_runtime.h>

// Wong-Wang multi-class decision model.
// Layout: 8 lanes per batch row (channel = lane & 7), 32768 threads total.
// Row-sum of s via 3 DPP adds within each 8-lane group.
// 16-deep register prefetch of eps (the only large input, 131 MB).

#define DPP_QUAD_XOR1   0xB1   // quad_perm [1,0,3,2]
#define DPP_QUAD_XOR2   0x4E   // quad_perm [2,3,0,1]
#define DPP_HALF_MIRROR 0x141  // reverse within 8 lanes (crosses the two quads)

template <int CTRL>
__device__ __forceinline__ float dpp_add(float v) {
    int moved = __builtin_amdgcn_update_dpp(0, __float_as_int(v), CTRL, 0xF, 0xF, true);
    return v + __int_as_float(moved);
}

__global__ void __launch_bounds__(64) ww_decision_kernel(
    const float* __restrict__ x,
    const float* __restrict__ eps0,
    const float* __restrict__ eps,
    const float* __restrict__ J,
    const float* __restrict__ pJext,
    const float* __restrict__ pI0,
    const float* __restrict__ pNa,
    const float* __restrict__ pThr,
    float* __restrict__ out)
{
    const int g = blockIdx.x * 64 + threadIdx.x;   // 0..32767 ; b = g>>3, c = g&7

    // Runtime parameters (uniform -> scalar loads)
    const float Jd     = J[0];        // diagonal value
    const float Jo     = J[8];        // off-diagonal value (J[1][0])
    const float Jdelta = Jd - Jo;
    const float I0     = pI0[0];
    const float na     = pNa[0];
    const float thr    = pThr[0];
    const float Jext   = pJext[0];

    // Constants (DT=0.5, TAU_AMPA=2, TAU_S=100, GAMMA=0.641, D=0.154, A=270, B=108)
    const float decay  = 0.7788007830714049f;            // exp(-DT/TAU_AMPA)
    const float nscale = na * 0.44354782138690364f;      // na*sqrt((1-exp(-2*DT/TAU_AMPA))/2)
    const float cD     = -0.2221750362969060f;           // -D * log2(e)
    const float K1     = 0.995f;                         // 1 - DT/TAU_S
    const float K2     = 0.0003205f;                     // DT*GAMMA/1000

    float s    = 0.1f;
    float In   = eps0[g] * na;
    float base = fmaf(Jext, x[g], I0);                   // I0 + I_ext (constant per lane)
    int   dec  = 999;                                    // T-1 default (never crossed)

#define WW_STEP(EK, TT)                                                      \
    {                                                                        \
        float S_ = dpp_add<DPP_QUAD_XOR1>(s);                                \
        S_ = dpp_add<DPP_QUAD_XOR2>(S_);                                     \
        S_ = dpp_add<DPP_HALF_MIRROR>(S_);   /* full 8-channel sum */        \
        float acc = base + In;                                               \
        acc = fmaf(Jo, S_, acc);                                             \
        acc = fmaf(Jdelta, s, acc);          /* s@J + I0 + Iext + In */      \
        float u  = fmaf(270.0f, acc, -108.0f);                               \
        float ex = __builtin_amdgcn_exp2f(u * cD);       /* exp(-D*u) */     \
        float den = (1.0f - ex) + 1e-6f;                                     \
        float H  = u * __builtin_amdgcn_rcpf(den);                           \
        H = fmaxf(H, 0.0f);                                                  \
        float sn = fmaf(K2 * (1.0f - s), H, s * K1);     /* s + dsdt*DT */   \
        In = fmaf(nscale, (EK), In * decay);                                 \
        s  = sn;                                                             \
        int cand = (sn > thr) ? (TT) : 999;                                  \
        dec = (cand < dec) ? cand : dec;                                     \
    }

    const float* ep = eps + g;          // eps[t][b][c] at offset t*32768 + g
    float ebuf[16];
#pragma unroll
    for (int k = 0; k < 16; ++k)
        ebuf[k] = ep[(size_t)k * 32768];

    int t = 0;
#pragma unroll 1
    for (int chunk = 0; chunk < 62; ++chunk) {          // 62*16 = 992 steps
#pragma unroll
        for (int k = 0; k < 16; ++k) {
            float ek = ebuf[k];
            int tf = t + 16;
            tf = (tf > 999) ? 999 : tf;                  // clamp prefetch (tail refills harmless)
            ebuf[k] = ep[(size_t)tf * 32768];
            WW_STEP(ek, t);
            ++t;
        }
    }
#pragma unroll
    for (int k = 0; k < 8; ++k) {                        // steps 992..999
        WW_STEP(ebuf[k], t);
        ++t;
    }

    out[g] = (float)dec * 0.0005f;                       // dec * DT / 1000
#undef WW_STEP
}

extern "C" void kernel_launch(void* const* d_in, const int* in_sizes, int n_in,
                              void* d_out, int out_size, void* d_ws, size_t ws_size,
                              hipStream_t stream) {
    const float* x    = (const float*)d_in[0];
    const float* eps0 = (const float*)d_in[1];
    const float* eps  = (const float*)d_in[2];
    const float* J    = (const float*)d_in[3];
    const float* Jext = (const float*)d_in[4];
    const float* I0   = (const float*)d_in[5];
    const float* na   = (const float*)d_in[6];
    const float* thr  = (const float*)d_in[7];
    float* out = (float*)d_out;

    dim3 grid(512), block(64);   // 32768 threads = one lane per (b, c)
    hipLaunchKernelGGL(ww_decision_kernel, grid, block, 0, stream,
                       x, eps0, eps, J, Jext, I0, na, thr, out);
}

// Round 2
// 62.829 us; speedup vs baseline: 1.1741x; 1.1741x over previous
//
#include <hip/hip_runtime.h>

// Wong-Wang multi-class decision model — chain-latency-optimized.
// Layout: 8 lanes per batch row (channel = lane & 7), 32768 threads = 512 waves.
// All lanes run their serial 1000-step chain in parallel (occupancy grid-limited);
// wall time == per-step dependency chain, so every change here targets the chain:
//   s -> 3xDPP sum -> 2 parallel fma chains (u, exp-arg) -> exp2 -> sub -> rcp -> fma -> max
// In/dec/load bookkeeping kept off the critical path.

#define DPP_QUAD_XOR1   0xB1   // quad_perm [1,0,3,2]
#define DPP_QUAD_XOR2   0x4E   // quad_perm [2,3,0,1]
#define DPP_HALF_MIRROR 0x141  // reverse within 8 lanes

template <int CTRL>
__device__ __forceinline__ float dpp_add(float v) {
    int moved = __builtin_amdgcn_update_dpp(0, __float_as_int(v), CTRL, 0xF, 0xF, true);
    return v + __int_as_float(moved);
}

__global__ void __launch_bounds__(64) ww_decision_kernel(
    const float* __restrict__ x,
    const float* __restrict__ eps0,
    const float* __restrict__ eps,
    const float* __restrict__ J,
    const float* __restrict__ pJext,
    const float* __restrict__ pI0,
    const float* __restrict__ pNa,
    const float* __restrict__ pThr,
    float* __restrict__ out)
{
    const int g = blockIdx.x * 64 + threadIdx.x;   // 0..32767 ; b = g>>3, c = g&7

    // Runtime parameters (uniform -> scalar loads)
    const float Jd     = J[0];
    const float Jo     = J[8];
    const float Jdelta = Jd - Jo;
    const float I0     = pI0[0];
    const float na     = pNa[0];
    const float thr    = pThr[0];
    const float Jext   = pJext[0];

    // Constants (DT=0.5, TAU_AMPA=2, TAU_S=100, GAMMA=0.641, D=0.154, A=270, B=108)
    const float decay  = 0.7788007830714049f;            // exp(-DT/TAU_AMPA)
    const float nscale = na * 0.44354782138690364f;      // na*sqrt((1-exp(-2DT/TAU_AMPA))/2)
    const float K1     = 0.995f;                         // 1 - DT/TAU_S
    const float K2     = 0.0003205f;                     // DT*GAMMA/1000
    const float K_ONE  = 1.000001f;                      // (1 + 1e-6) folded

    // Pre-fused chain constants:  u = A*acc - B ;  earg = cD*u,  cD = -D*log2(e)
    const float cDA    = -59.98725980016364f;            // cD * 270
    const float AJo    = 270.0f * Jo;
    const float AJd    = 270.0f * Jdelta;
    const float cDAJo  = cDA * Jo;
    const float cDAJd  = cDA * Jdelta;

    float s    = 0.1f;
    float In   = eps0[g] * na;
    const float base = fmaf(Jext, x[g], I0);             // I0 + I_ext per lane
    const float ub   = fmaf(270.0f, base, -108.0f);      // A*base - B
    const float eb   = fmaf(cDA, base, 23.994903920065457f);  // cDA*base - cD*B
    int   dec  = 999;

#define WW_STEP(EK, TT)                                                      \
    {                                                                        \
        /* off-path: In-dependent offsets (In known from prev step) */       \
        float cu = fmaf(270.0f, In, ub);                                     \
        float ce = fmaf(cDA,    In, eb);                                     \
        float km  = fmaf(-K2, s, K2);          /* K2*(1-s) >= 0 */           \
        float k1s = s * K1;                                                  \
        /* critical path: tree -> fma -> exp2 -> sub -> rcp -> fma -> max */ \
        float S1 = dpp_add<DPP_QUAD_XOR1>(s);                                \
        float S2 = dpp_add<DPP_QUAD_XOR2>(S1);                               \
        float S_ = dpp_add<DPP_HALF_MIRROR>(S2);                             \
        float ui = fmaf(AJd,   s, cu);                                       \
        float ei = fmaf(cDAJd, s, ce);                                       \
        float u    = fmaf(AJo,   S_, ui);                                    \
        float earg = fmaf(cDAJo, S_, ei);                                    \
        float ex  = __builtin_amdgcn_exp2f(earg);        /* exp(-D*u) */     \
        float den = K_ONE - ex;                                              \
        float r   = __builtin_amdgcn_rcpf(den);                              \
        float p   = u * km;                    /* parallel with rcp */       \
        float sn  = fmaf(p, r, k1s);                                         \
        sn = fmaxf(sn, k1s);                   /* == s+dt*dsdt with relu */  \
        In = fmaf(nscale, (EK), In * decay);                                 \
        int cand = (sn > thr) ? (TT) : 999;                                  \
        dec = (cand < dec) ? cand : dec;                                     \
        s  = sn;                                                             \
    }

    const float* ep = eps + g;              // eps[t][b][c] at offset t*32768 + g
    float ebuf[16];
#pragma unroll
    for (int k = 0; k < 16; ++k)
        ebuf[k] = ep[(size_t)k * 32768];

    int t = 0;
#pragma unroll 1
    for (int chunk = 0; chunk < 61; ++chunk) {          // steps 0..975
#pragma unroll
        for (int k = 0; k < 16; ++k) {
            float ek = ebuf[k];
            ebuf[k] = ep[(size_t)(t + 16) * 32768];      // loads 16..991
            WW_STEP(ek, t);
            ++t;
        }
    }
    // tail chunk: steps 976..991; prefetch 992..999 during first 8 steps
#pragma unroll
    for (int k = 0; k < 16; ++k) {
        float ek = ebuf[k];
        if (k < 8)
            ebuf[k] = ep[(size_t)(t + 16) * 32768];
        WW_STEP(ek, t);
        ++t;
    }
#pragma unroll
    for (int k = 0; k < 8; ++k) {                        // steps 992..999
        WW_STEP(ebuf[k], t);
        ++t;
    }

    out[g] = (float)dec * 0.0005f;                       // dec * DT / 1000
#undef WW_STEP
}

extern "C" void kernel_launch(void* const* d_in, const int* in_sizes, int n_in,
                              void* d_out, int out_size, void* d_ws, size_t ws_size,
                              hipStream_t stream) {
    const float* x    = (const float*)d_in[0];
    const float* eps0 = (const float*)d_in[1];
    const float* eps  = (const float*)d_in[2];
    const float* J    = (const float*)d_in[3];
    const float* Jext = (const float*)d_in[4];
    const float* I0   = (const float*)d_in[5];
    const float* na   = (const float*)d_in[6];
    const float* thr  = (const float*)d_in[7];
    float* out = (float*)d_out;

    dim3 grid(512), block(64);   // 32768 threads = one lane per (b, c)
    hipLaunchKernelGGL(ww_decision_kernel, grid, block, 0, stream,
                       x, eps0, eps, J, Jext, I0, na, thr, out);
}